// Round 4
// baseline (2508.034 us; speedup 1.0000x reference)
//
#include <hip/hip_runtime.h>
#include <math.h>

#define SEQ   2048
#define BATCH 128
#define HID   256
#define VPAD  36   // v chunk stride (32 data + 4 pad floats); b128 reads conflict-free

// One block of 256 threads (4 waves, 1 wave/SIMD -> 512 VGPR budget) per batch.
// Thread (rg=tid>>3, kc=tid&7): computes 8 row-partials over k-chunk
// [32kc,32kc+32). Weight rows are loaded in XOR-relative order:
//   wreg[j] = W_eff[8rg + (kc^j)][32kc..+32)   (256 fp32 in VGPRs)
// so the 8x8 partial reduction is an in-wave butterfly transpose-reduce:
//   q[j] += shfl_xor(q[j^m], m) for m=4,2,1 (7 shfls) -> thread tid ends with
// the full dot for row tid. No partials LDS array, ONE barrier per step
// (v = 2h-1 is double-buffered in LDS).
// Round-2 counters showed LDS-pipe-bound (~776 cyc/step); this cuts LDS to
// ~550 cyc/step (v-reads 384 + shfl) balanced against VALU 512.
__global__ __launch_bounds__(256, 1)
void rnn_scan_kernel(const float* __restrict__ x,        // (SEQ, BATCH)
                     const float* __restrict__ h0,       // (BATCH, HID)
                     const float* __restrict__ W_ih,     // (HID, 1)
                     const float* __restrict__ W_hh,     // (HID, HID)
                     const float* __restrict__ W_hh_b,   // (HID, HID)
                     const float* __restrict__ b_h,      // (HID,)
                     const int*   __restrict__ context,  // scalar
                     float*       __restrict__ out_hs)   // (BATCH, SEQ, HID)
{
    const int b   = blockIdx.x;
    const int tid = threadIdx.x;
    const int rg  = tid >> 3;   // row-group: rows [8rg, 8rg+8)
    const int kc  = tid & 7;    // k-chunk:   k in [32kc, 32kc+32)

    __shared__ __align__(16) float v_lds[2][8 * VPAD];  // 2h-1, double-buffered
    __shared__ float x_lds[SEQ];

    for (int t = tid; t < SEQ; t += 256)
        x_lds[t] = x[t * BATCH + b];

    const float ctx = (float)context[0];

    // wreg[j][c] = W_eff[8rg + (kc^j)][32kc + 4c .. +3]  (XOR-relative rows)
    float4 wreg[8][8];
    #pragma unroll
    for (int j = 0; j < 8; ++j) {
        const int row = 8 * rg + (kc ^ j);
        const float* wp = W_hh   + (size_t)row * HID + 32 * kc;
        const float* bp = W_hh_b + (size_t)row * HID + 32 * kc;
        #pragma unroll
        for (int c = 0; c < 8; ++c) {
            const float4 a = *(const float4*)(wp + 4 * c);
            const float4 d = *(const float4*)(bp + 4 * c);
            wreg[j][c] = make_float4(a.x + ctx * d.x, a.y + ctx * d.y,
                                     a.z + ctx * d.z, a.w + ctx * d.w);
        }
    }

    // Thread tid owns row tid's recurrent state.
    float h = h0[(size_t)b * HID + tid];
    const float winj = W_ih[tid];
    const float bhj  = b_h[tid];

    const int vslot = VPAD * (tid >> 5) + (tid & 31);   // <=2-way write (free)
    v_lds[0][vslot] = 2.f * h - 1.f;

    float* outp = out_hs + (size_t)b * SEQ * HID + tid;
    const float4* vb0 = (const float4*)(v_lds[0] + VPAD * kc);  // 144B-aligned
    const float4* vb1 = (const float4*)(v_lds[1] + VPAD * kc);

    __syncthreads();  // v[0] + x_lds ready

    for (int t = 0; t < SEQ; ++t) {
        const float4* vb = (t & 1) ? vb1 : vb0;

        // Partial dots: 8 broadcast b128 v-reads, 256 FMAs.
        float q[8] = {0.f, 0.f, 0.f, 0.f, 0.f, 0.f, 0.f, 0.f};
        #pragma unroll
        for (int c = 0; c < 8; ++c) {
            const float4 v4 = vb[c];
            #pragma unroll
            for (int j = 0; j < 8; ++j) {
                const float4 w = wreg[j][c];
                q[j] += w.x * v4.x;
                q[j] += w.y * v4.y;
                q[j] += w.z * v4.z;
                q[j] += w.w * v4.w;
            }
        }
        // In-wave transpose-reduce over the 8-lane kc-group:
        // after m=4,2,1 rounds, q[0] = full dot for row 8rg+kc = tid.
        q[0] += __shfl_xor(q[4], 4, 64);
        q[1] += __shfl_xor(q[5], 4, 64);
        q[2] += __shfl_xor(q[6], 4, 64);
        q[3] += __shfl_xor(q[7], 4, 64);
        q[0] += __shfl_xor(q[2], 2, 64);
        q[1] += __shfl_xor(q[3], 2, 64);
        q[0] += __shfl_xor(q[1], 1, 64);

        const float pre = q[0] + bhj + x_lds[t] * winj;
        h = 1.f / (1.f + __expf(-pre));
        outp[(size_t)t * HID] = h;                  // coalesced 1KB store
        v_lds[(t + 1) & 1][vslot] = 2.f * h - 1.f;  // other buffer: no WAR race

        __syncthreads();  // v[t+1] ready; buffer t fully read before reuse
    }
}

// y[r] = dot(hs[r,:], W[0,:]) + bias[0]. 16 lanes per row, 4 rows per wave;
// each lane covers 16 floats (4 float4s, 16B-stride coalesced within the
// 16-lane group), shfl-xor tree over 16 lanes. Full 256-element coverage:
// lane sub, chunk u -> elements 4*(16u+sub)..+3; u=0..3, sub=0..15 spans 0..255.
__global__ __launch_bounds__(256, 4)
void head_kernel(const float* __restrict__ hs,   // (BATCH*SEQ, HID)
                 const float* __restrict__ W,    // (OUTD, HID)
                 const float* __restrict__ bias, // (OUTD,)
                 float*       __restrict__ y)    // (BATCH*SEQ,)
{
    const int tid  = threadIdx.x;
    const int lane = tid & 63;
    const int sub  = lane & 15;    // position within row
    const int rsub = lane >> 4;    // row within quad

    float4 w0[4];
    #pragma unroll
    for (int u = 0; u < 4; ++u)
        w0[u] = *(const float4*)(W + 4 * (16 * u + sub));
    const float b0 = bias[0];

    const int gwave = (blockIdx.x * blockDim.x + tid) >> 6;
    const int nw    = (gridDim.x * blockDim.x) >> 6;
    const int nq    = (BATCH * SEQ) >> 2;   // row quads

    for (int q = gwave; q < nq; q += nw) {
        const int row = q * 4 + rsub;
        const float* rp = hs + (size_t)row * HID;
        float s = 0.f;
        #pragma unroll
        for (int u = 0; u < 4; ++u) {
            const float4 hv = *(const float4*)(rp + 4 * (16 * u + sub));
            s += hv.x * w0[u].x + hv.y * w0[u].y +
                 hv.z * w0[u].z + hv.w * w0[u].w;
        }
        s += __shfl_xor(s, 1, 64);
        s += __shfl_xor(s, 2, 64);
        s += __shfl_xor(s, 4, 64);
        s += __shfl_xor(s, 8, 64);
        if (sub == 0) y[row] = s + b0;   // lanes 0,16,32,48: 4 adjacent floats
    }
}

extern "C" void kernel_launch(void* const* d_in, const int* in_sizes, int n_in,
                              void* d_out, int out_size, void* d_ws, size_t ws_size,
                              hipStream_t stream) {
    const float* x      = (const float*)d_in[0];
    const float* h0     = (const float*)d_in[1];
    const float* W_ih   = (const float*)d_in[2];
    const float* W_hh   = (const float*)d_in[3];
    const float* W_hh_b = (const float*)d_in[4];
    const float* b_h    = (const float*)d_in[5];
    const float* W      = (const float*)d_in[6];
    const float* bias   = (const float*)d_in[7];
    const int*   ctx    = (const int*)d_in[8];

    float* y  = (float*)d_out;                // (BATCH*SEQ,) = y[:,:,0]
    float* hs = y + (size_t)BATCH * SEQ;      // (BATCH, SEQ, HID) = out

    rnn_scan_kernel<<<BATCH, HID, 0, stream>>>(x, h0, W_ih, W_hh, W_hh_b,
                                               b_h, ctx, hs);
    head_kernel<<<2048, 256, 0, stream>>>(hs, W, bias, y);
}

// Round 6
// 1443.016 us; speedup vs baseline: 1.7381x; 1.7381x over previous
//
#include <hip/hip_runtime.h>
#include <math.h>

#define SEQ   2048
#define BATCH 128
#define HID   256
#define NCH   16   // k-chunks
#define KCH   16   // floats per chunk
#define VST   20   // chunk stride in floats (80B): 16 chunk bases -> 8 bank
                   // quads x 2 addrs = 2-way max on b128 reads (free, m136)

// dst = src's value from lane (lane XOR pattern) via DPP (VALU pipe, no LDS).
// 0xB1 = quad_perm [1,0,3,2] (xor1); 0x4E = quad_perm [2,3,0,1] (xor2);
// 0x128 = row_ror:8 == xor8 within each 16-lane row.
template <int CTRL>
__device__ __forceinline__ float dpp_mov(float x) {
    return __int_as_float(__builtin_amdgcn_update_dpp(
        __float_as_int(x), __float_as_int(x), CTRL, 0xF, 0xF, false));
}
__device__ __forceinline__ float swz_xor4(float x) {   // lane ^ 4 (LDS pipe)
    return __int_as_float(__builtin_amdgcn_ds_swizzle(__float_as_int(x), 0x101F));
}

// One block (512 threads, 8 waves, 2 waves/SIMD) per batch element. fp32.
// Thread (R=tid>>4, l=tid&15): k-chunk [16l,16l+16), rows 8R+((tid&7)^j),
// j=0..7 -> 128 weight fp32 in VGPRs (fits 256-cap; waves_per_eu(2,2) pins
// the allocator so it can't chase occupancy and spill — round-2/4 lesson).
// Reduce without LDS partials: fold l<->l^8 (DPP row_ror:8, same rows /
// complementary chunks), then XOR transpose small-mask-first (mask1 x4,
// mask2 x2 via DPP quad_perm; mask4 x1 via ds_swizzle) -> lane ends with the
// full dot of row 8R+(tid&7). Threads tid and tid^8 duplicate the same row
// bitwise-identically (commutative fold): LDS v-write duplicated (benign),
// global store predicated on (tid&8)==0.
// v = 2h-1 fp32, double-buffered, ONE barrier/step; K-loop unrolled x2 so
// buffer pointers are static.
__global__ __launch_bounds__(512) __attribute__((amdgpu_waves_per_eu(2, 2)))
void rnn_scan_kernel(const float* __restrict__ x,        // (SEQ, BATCH)
                     const float* __restrict__ h0,       // (BATCH, HID)
                     const float* __restrict__ W_ih,     // (HID, 1)
                     const float* __restrict__ W_hh,     // (HID, HID)
                     const float* __restrict__ W_hh_b,   // (HID, HID)
                     const float* __restrict__ b_h,      // (HID,)
                     const int*   __restrict__ context,  // scalar
                     float*       __restrict__ out_hs)   // (BATCH, SEQ, HID)
{
    const int b   = blockIdx.x;
    const int tid = threadIdx.x;
    const int R   = tid >> 4;    // row-group: rows [8R, 8R+8)
    const int l   = tid & 15;    // k-chunk index
    const int l7  = tid & 7;
    const int row = 8 * R + l7;  // row this thread owns after the reduce

    __shared__ __align__(16) float v_lds[2][NCH * VST];
    __shared__ float x_lds[SEQ];

    for (int t = tid; t < SEQ; t += 512)
        x_lds[t] = x[t * BATCH + b];

    const float ctx = (float)context[0];

    // wreg[j][c] = W_eff[8R + (l7^j)][16l + 4c .. +3]  (XOR-ordered rows)
    float4 wreg[8][4];
    #pragma unroll
    for (int j = 0; j < 8; ++j) {
        const int rj = 8 * R + (l7 ^ j);
        const float* wp = W_hh   + (size_t)rj * HID + KCH * l;
        const float* bp = W_hh_b + (size_t)rj * HID + KCH * l;
        #pragma unroll
        for (int c = 0; c < 4; ++c) {
            const float4 a = *(const float4*)(wp + 4 * c);
            const float4 d = *(const float4*)(bp + 4 * c);
            wreg[j][c] = make_float4(a.x + ctx * d.x, a.y + ctx * d.y,
                                     a.z + ctx * d.z, a.w + ctx * d.w);
        }
    }

    const float winj = W_ih[row];
    const float bhj  = b_h[row];

    const int voff = VST * (row >> 4) + (row & 15);
    v_lds[0][voff] = 2.f * h0[(size_t)b * HID + row] - 1.f;  // dup-safe

    float* outp = out_hs + (size_t)b * SEQ * HID + row;

    const float4* vr0 = (const float4*)(v_lds[0] + VST * l);  // 80B-stride, 16B-aligned
    const float4* vr1 = (const float4*)(v_lds[1] + VST * l);

    __syncthreads();  // v[0] + x_lds ready

    auto step = [&](int t, const float4* __restrict__ vr, float* __restrict__ vw) {
        float q[8] = {0.f, 0.f, 0.f, 0.f, 0.f, 0.f, 0.f, 0.f};
        #pragma unroll
        for (int c = 0; c < 4; ++c) {
            const float4 v4 = vr[c];
            #pragma unroll
            for (int j = 0; j < 8; ++j) {
                const float4 w = wreg[j][c];
                q[j] += w.x * v4.x;
                q[j] += w.y * v4.y;
                q[j] += w.z * v4.z;
                q[j] += w.w * v4.w;
            }
        }
        // Fold l <-> l^8: same rows, complementary k-halves (VALU/DPP).
        #pragma unroll
        for (int j = 0; j < 8; ++j) q[j] += dpp_mov<0x128>(q[j]);
        // XOR transpose-reduce, small masks first (only mask4 needs LDS).
        q[0] += dpp_mov<0xB1>(q[1]);
        q[2] += dpp_mov<0xB1>(q[3]);
        q[4] += dpp_mov<0xB1>(q[5]);
        q[6] += dpp_mov<0xB1>(q[7]);
        q[0] += dpp_mov<0x4E>(q[2]);
        q[4] += dpp_mov<0x4E>(q[6]);
        q[0] += swz_xor4(q[4]);
        // q[0] = full dot for row 8R + l7 (dup in tid and tid^8, bit-identical)

        const float pre = q[0] + bhj + x_lds[t] * winj;
        const float h = 1.f / (1.f + __expf(-pre));
        vw[voff] = 2.f * h - 1.f;                 // dup write, same value: benign
        if ((tid & 8) == 0)
            outp[(size_t)t * HID] = h;            // 32 lanes/wave, rows 32w..+32
        __syncthreads();  // v for t+1 ready; buffer t fully read before reuse
    };

    for (int t = 0; t < SEQ; t += 2) {
        step(t,     vr0, v_lds[1]);
        step(t + 1, vr1, v_lds[0]);
    }
}

// y[r] = dot(hs[r,:], W[0,:]) + bias[0]. 16 lanes/row, 4 rows/wave; each lane
// covers 16 floats; shfl-xor tree over 16 lanes. (Validated round 4.)
__global__ __launch_bounds__(256, 4)
void head_kernel(const float* __restrict__ hs,   // (BATCH*SEQ, HID)
                 const float* __restrict__ W,    // (OUTD, HID)
                 const float* __restrict__ bias, // (OUTD,)
                 float*       __restrict__ y)    // (BATCH*SEQ,)
{
    const int tid  = threadIdx.x;
    const int lane = tid & 63;
    const int sub  = lane & 15;
    const int rsub = lane >> 4;

    float4 w0[4];
    #pragma unroll
    for (int u = 0; u < 4; ++u)
        w0[u] = *(const float4*)(W + 4 * (16 * u + sub));
    const float b0 = bias[0];

    const int gwave = (blockIdx.x * blockDim.x + tid) >> 6;
    const int nw    = (gridDim.x * blockDim.x) >> 6;
    const int nq    = (BATCH * SEQ) >> 2;

    for (int q = gwave; q < nq; q += nw) {
        const int rrow = q * 4 + rsub;
        const float* rp = hs + (size_t)rrow * HID;
        float s = 0.f;
        #pragma unroll
        for (int u = 0; u < 4; ++u) {
            const float4 hv = *(const float4*)(rp + 4 * (16 * u + sub));
            s += hv.x * w0[u].x + hv.y * w0[u].y +
                 hv.z * w0[u].z + hv.w * w0[u].w;
        }
        s += __shfl_xor(s, 1, 64);
        s += __shfl_xor(s, 2, 64);
        s += __shfl_xor(s, 4, 64);
        s += __shfl_xor(s, 8, 64);
        if (sub == 0) y[rrow] = s + b0;
    }
}

extern "C" void kernel_launch(void* const* d_in, const int* in_sizes, int n_in,
                              void* d_out, int out_size, void* d_ws, size_t ws_size,
                              hipStream_t stream) {
    const float* x      = (const float*)d_in[0];
    const float* h0     = (const float*)d_in[1];
    const float* W_ih   = (const float*)d_in[2];
    const float* W_hh   = (const float*)d_in[3];
    const float* W_hh_b = (const float*)d_in[4];
    const float* b_h    = (const float*)d_in[5];
    const float* W      = (const float*)d_in[6];
    const float* bias   = (const float*)d_in[7];
    const int*   ctx    = (const int*)d_in[8];

    float* y  = (float*)d_out;                // (BATCH*SEQ,) = y[:,:,0]
    float* hs = y + (size_t)BATCH * SEQ;      // (BATCH, SEQ, HID) = out

    rnn_scan_kernel<<<BATCH, 512, 0, stream>>>(x, h0, W_ih, W_hh, W_hh_b,
                                               b_h, ctx, hs);
    head_kernel<<<2048, 256, 0, stream>>>(hs, W, bias, y);
}